// Round 5
// baseline (497.859 us; speedup 1.0000x reference)
//
#include <hip/hip_runtime.h>
#include <cstdint>

// SpacetimeNonLocalBlock: B=4, C=256, T*H*W=N=6272, IC=128.
// R4: BISECTION round. Everything is R2-verbatim (the version that PASSED at
// 497 us / absmax 0.03125) except ONE concept: flash2 is k-split x2 (KSPL=2,
// kb offset, 49 iters instead of 98) and writes unnormalized fp32 partial O
// plus per-column (m,l); a merge kernel combines splits exactly.
// R3's simultaneous micro-changes (TK=32, SW swizzle, V-stride-40, f16
// partials, transposed proj LDS) are all REVERTED to isolate its bug.
// ws: Qg|Kg|Vtg f16 (19.27 MB) | Opart f32 2x12.85 MB | Mpart,Lpart f32
//     (0.2 MB) = 45.2 MB; Yt f32 (12.85 MB) overlays Qg+Kg after flash2.

#define BB   4
#define CCH  256
#define NPOS 6272
#define ICH  128
#define BNIC ((size_t)BB * NPOS * ICH)
#define KSPL 2
#define KLEN (NPOS / KSPL)   // 3136
#define TKF  64
#define NITK (KLEN / TKF)    // 49

typedef __attribute__((ext_vector_type(8)))  _Float16 h8v;  // 8 f16 MFMA frag
typedef __attribute__((ext_vector_type(16))) float fx16;    // 32x32 acc

__device__ __forceinline__ unsigned short f2h(float f) {    // RNE fp32->fp16
  _Float16 h = (_Float16)f;
  return __builtin_bit_cast(unsigned short, h);
}
__device__ __forceinline__ unsigned int pkh(float lo, float hi) {
  return __builtin_bit_cast(unsigned int, __builtin_amdgcn_cvt_pkrtz(lo, hi));
}

// ---------------------------------------------------------------------------
// proj_qk (R2-verbatim): Q/K [b][n][128] f16.
// ---------------------------------------------------------------------------
__global__ __launch_bounds__(256, 2)
void proj_qk(const float* __restrict__ x,
             const float* __restrict__ Wtheta,
             const float* __restrict__ Wphi,
             unsigned short* __restrict__ Qg,
             unsigned short* __restrict__ Kg) {
  const int n0 = blockIdx.x * 64;
  const int p  = blockIdx.y >> 1;
  const int o_half = (blockIdx.y & 1) * 64;
  const int b  = blockIdx.z;
  const float* W = p ? Wphi : Wtheta;
  unsigned short* Out = p ? Kg : Qg;

  __shared__ float Xt[64][17];
  __shared__ float Wt[64][17];
  const int tid = threadIdx.x;
  const int tx = tid & 15, ty = tid >> 4;
  float acc[4][4] = {};

  for (int c0 = 0; c0 < CCH; c0 += 16) {
    {
      const int nn = tid & 63, k4 = tid >> 6;
      #pragma unroll
      for (int q = 0; q < 4; ++q) {
        const int kk = k4 + q * 4;
        Xt[nn][kk] = x[((size_t)(b * CCH + c0 + kk)) * NPOS + n0 + nn];
      }
      const int wk = tid & 15, wo = tid >> 4;
      #pragma unroll
      for (int q = 0; q < 4; ++q) {
        const int oo = wo + q * 16;
        Wt[oo][wk] = W[(size_t)(o_half + oo) * CCH + c0 + wk];
      }
    }
    __syncthreads();
    #pragma unroll
    for (int kk = 0; kk < 16; ++kk) {
      float a_[4], b_[4];
      #pragma unroll
      for (int i = 0; i < 4; ++i) a_[i] = Xt[ty * 4 + i][kk];
      #pragma unroll
      for (int j = 0; j < 4; ++j) b_[j] = Wt[tx * 4 + j][kk];
      #pragma unroll
      for (int i = 0; i < 4; ++i)
        #pragma unroll
        for (int j = 0; j < 4; ++j) acc[i][j] += a_[i] * b_[j];
    }
    __syncthreads();
  }
  #pragma unroll
  for (int i = 0; i < 4; ++i) {
    ushort4 v;
    v.x = f2h(acc[i][0]); v.y = f2h(acc[i][1]);
    v.z = f2h(acc[i][2]); v.w = f2h(acc[i][3]);
    *(ushort4*)&Out[((size_t)b * NPOS + n0 + ty * 4 + i) * ICH + o_half + tx * 4] = v;
  }
}

// ---------------------------------------------------------------------------
// proj_v (R2-verbatim): V^T [b][128][N] f16.
// ---------------------------------------------------------------------------
__global__ __launch_bounds__(256, 2)
void proj_v(const float* __restrict__ x,
            const float* __restrict__ Wg,
            unsigned short* __restrict__ Vtg) {
  const int n0 = blockIdx.x * 64;
  const int o_half = blockIdx.y * 64;
  const int b  = blockIdx.z;
  __shared__ float Xt[64][17];
  __shared__ float Wt[64][17];
  const int tid = threadIdx.x;
  const int tx = tid & 15, ty = tid >> 4;
  float acc[4][4] = {};   // rows o = ty*4+i, cols n = tx*4+j

  for (int c0 = 0; c0 < CCH; c0 += 16) {
    {
      const int nn = tid & 63, k4 = tid >> 6;
      #pragma unroll
      for (int q = 0; q < 4; ++q) {
        const int kk = k4 + q * 4;
        Xt[nn][kk] = x[((size_t)(b * CCH + c0 + kk)) * NPOS + n0 + nn];
      }
      const int wk = tid & 15, wo = tid >> 4;
      #pragma unroll
      for (int q = 0; q < 4; ++q) {
        const int oo = wo + q * 16;
        Wt[oo][wk] = Wg[(size_t)(o_half + oo) * CCH + c0 + wk];
      }
    }
    __syncthreads();
    #pragma unroll
    for (int kk = 0; kk < 16; ++kk) {
      float a_[4], b_[4];
      #pragma unroll
      for (int i = 0; i < 4; ++i) a_[i] = Wt[ty * 4 + i][kk];
      #pragma unroll
      for (int j = 0; j < 4; ++j) b_[j] = Xt[tx * 4 + j][kk];
      #pragma unroll
      for (int i = 0; i < 4; ++i)
        #pragma unroll
        for (int j = 0; j < 4; ++j) acc[i][j] += a_[i] * b_[j];
    }
    __syncthreads();
  }
  #pragma unroll
  for (int i = 0; i < 4; ++i) {
    ushort4 v;
    v.x = f2h(acc[i][0]); v.y = f2h(acc[i][1]);
    v.z = f2h(acc[i][2]); v.w = f2h(acc[i][3]);
    *(ushort4*)&Vtg[((size_t)b * ICH + o_half + ty * 4 + i) * NPOS + n0 + tx * 4] = v;
  }
}

// ---------------------------------------------------------------------------
// flash2: R2-verbatim body; ONLY delta = kb offset (k-split), 49 iters,
// epilogue -> unnormalized fp32 Opart + (m,l). grid (49, KSPL, B).
// ---------------------------------------------------------------------------
__global__ __launch_bounds__(256, 1)
void flash2(const unsigned short* __restrict__ Qg,
            const unsigned short* __restrict__ Kg,
            const unsigned short* __restrict__ Vtg,
            float* __restrict__ Opart,
            float* __restrict__ Mpart,
            float* __restrict__ Lpart) {
  __shared__ unsigned short Ks[2][TKF * 128];   // [k-row][ch], 16 chunks/row
  __shared__ unsigned short Vs[2][128 * TKF];   // [d-row][k],  8 chunks/row

  const int b   = blockIdx.z;
  const int spl = blockIdx.y;
  const int n0  = blockIdx.x * 128;
  const int kb  = spl * KLEN;
  const int tid = threadIdx.x;
  const int lane = tid & 63, wv = tid >> 6;
  const int qlane = lane & 31, g = lane >> 5;
  const int swz = qlane & 7;

  // Q fragments in registers for the whole kernel (B-operand: B[ch][q])
  h8v qf[8];
  {
    const size_t qbase = ((size_t)b * NPOS + n0 + 32 * wv + qlane) * ICH;
    #pragma unroll
    for (int cs = 0; cs < 8; ++cs)
      qf[cs] = *(const h8v*)&Qg[qbase + cs * 16 + g * 8];
  }

  // prologue: stage tile 0 into buffer 0
  {
    #pragma unroll
    for (int s4 = 0; s4 < 4; ++s4) {
      const int kr = 16 * wv + 4 * s4 + (lane >> 4);
      const int kc = lane & 15;
      uint4 v = *(const uint4*)&Kg[((size_t)b * NPOS + kb + kr) * ICH + kc * 8];
      *(uint4*)&Ks[0][kr * 128 + ((kc ^ (kr & 7))) * 8] = v;
      const int dr = 32 * wv + 8 * s4 + (lane >> 3);
      const int dc = lane & 7;
      uint4 w = *(const uint4*)&Vtg[((size_t)b * ICH + dr) * NPOS + kb + dc * 8];
      *(uint4*)&Vs[0][dr * TKF + ((dc ^ (dr & 7))) * 8] = w;
    }
  }
  __syncthreads();

  float m_run = -1e30f, l_run = 0.0f;
  fx16 accO[4];
  #pragma unroll
  for (int mt = 0; mt < 4; ++mt) accO[mt] = (fx16)(0.0f);

  uint4 stgK[4], stgV[4];

  for (int it = 0; it < NITK; ++it) {
    const int cur = it & 1;
    const bool pre = (it + 1 < NITK);
    if (pre) {  // global loads for next tile; writes deferred past compute
      const int k0n = kb + (it + 1) * TKF;
      #pragma unroll
      for (int s4 = 0; s4 < 4; ++s4) {
        const int kr = 16 * wv + 4 * s4 + (lane >> 4);
        stgK[s4] = *(const uint4*)&Kg[((size_t)b * NPOS + k0n + kr) * ICH + (lane & 15) * 8];
        const int dr = 32 * wv + 8 * s4 + (lane >> 3);
        stgV[s4] = *(const uint4*)&Vtg[((size_t)b * ICH + dr) * NPOS + k0n + (lane & 7) * 8];
      }
    }

    // ---- S^T = K . Q^T : D[k][q], tiles mt = k 32-halves ----
    fx16 accS[2];
    accS[0] = (fx16)(0.0f); accS[1] = (fx16)(0.0f);
    #pragma unroll
    for (int cs = 0; cs < 8; ++cs) {
      #pragma unroll
      for (int mt = 0; mt < 2; ++mt) {
        const h8v aK = *(const h8v*)&Ks[cur][(32 * mt + qlane) * 128 + (((2 * cs + g) ^ swz)) * 8];
        accS[mt] = __builtin_amdgcn_mfma_f32_32x32x16_f16(aK, qf[cs], accS[mt], 0, 0, 0);
      }
    }

    // ---- online softmax (per lane: one q column; xor-32 merges k halves) ----
    float mx = accS[0][0];
    #pragma unroll
    for (int r = 1; r < 16; ++r) mx = fmaxf(mx, accS[0][r]);
    #pragma unroll
    for (int r = 0; r < 16; ++r) mx = fmaxf(mx, accS[1][r]);
    mx = fmaxf(mx, __shfl_xor(mx, 32));
    const float mn = fmaxf(m_run, mx);
    const float alpha = __expf(m_run - mn);
    float lsum = 0.0f;
    unsigned int pk[2][4][2];
    #pragma unroll
    for (int mt = 0; mt < 2; ++mt)
      #pragma unroll
      for (int u = 0; u < 4; ++u) {
        const float p0 = __expf(accS[mt][4 * u + 0] - mn);
        const float p1 = __expf(accS[mt][4 * u + 1] - mn);
        const float p2 = __expf(accS[mt][4 * u + 2] - mn);
        const float p3 = __expf(accS[mt][4 * u + 3] - mn);
        lsum += (p0 + p1) + (p2 + p3);
        pk[mt][u][0] = pkh(p0, p1);
        pk[mt][u][1] = pkh(p2, p3);
      }
    lsum += __shfl_xor(lsum, 32);
    l_run = l_run * alpha + lsum;
    m_run = mn;
    #pragma unroll
    for (int mt = 0; mt < 4; ++mt)
      #pragma unroll
      for (int r = 0; r < 16; ++r) accO[mt][r] *= alpha;

    // ---- PV: O^T += V^T . P^T ----
    #pragma unroll
    for (int s = 0; s < 4; ++s) {
      const int mtp = s >> 1, sb = s & 1;
      const unsigned int v0 = pk[mtp][2 * sb + (g ^ 1)][0];
      const unsigned int v1 = pk[mtp][2 * sb + (g ^ 1)][1];
      const unsigned int t0 = __shfl_xor(v0, 32);
      const unsigned int t1 = __shfl_xor(v1, 32);
      union { unsigned int u[4]; h8v v; } bP;
      bP.u[0] = g ? t0 : pk[mtp][2 * sb][0];
      bP.u[1] = g ? t1 : pk[mtp][2 * sb][1];
      bP.u[2] = g ? pk[mtp][2 * sb + 1][0] : t0;
      bP.u[3] = g ? pk[mtp][2 * sb + 1][1] : t1;
      #pragma unroll
      for (int mt = 0; mt < 4; ++mt) {
        const h8v aV = *(const h8v*)&Vs[cur][(32 * mt + qlane) * TKF + (((2 * s + g) ^ swz)) * 8];
        accO[mt] = __builtin_amdgcn_mfma_f32_32x32x16_f16(aV, bP.v, accO[mt], 0, 0, 0);
      }
    }

    if (pre) {  // commit staged tile to the other buffer
      const int nb = cur ^ 1;
      #pragma unroll
      for (int s4 = 0; s4 < 4; ++s4) {
        const int kr = 16 * wv + 4 * s4 + (lane >> 4);
        *(uint4*)&Ks[nb][kr * 128 + (((lane & 15) ^ (kr & 7))) * 8] = stgK[s4];
        const int dr = 32 * wv + 8 * s4 + (lane >> 3);
        *(uint4*)&Vs[nb][dr * TKF + (((lane & 7) ^ (dr & 7))) * 8] = stgV[s4];
      }
    }
    __syncthreads();
  }

  // epilogue: unnormalized fp32 partial O + per-column m,l
  const int ncol = n0 + 32 * wv + qlane;
  const size_t obase = (size_t)(b * KSPL + spl) * ICH * NPOS;
  #pragma unroll
  for (int mt = 0; mt < 4; ++mt)
    #pragma unroll
    for (int r = 0; r < 16; ++r) {
      const int d = 32 * mt + (r & 3) + 8 * (r >> 2) + 4 * g;
      Opart[obase + (size_t)d * NPOS + ncol] = accO[mt][r];
    }
  if (g == 0) {
    Mpart[(size_t)(b * KSPL + spl) * NPOS + ncol] = m_run;
    Lpart[(size_t)(b * KSPL + spl) * NPOS + ncol] = l_run;
  }
}

// ---------------------------------------------------------------------------
// merge: Y^T[b][d][n] = sum_s e^{m_s-M} O_s[d][n] / sum_s e^{m_s-M} l_s
// ---------------------------------------------------------------------------
__global__ __launch_bounds__(256, 2)
void merge_kernel(const float* __restrict__ Opart,
                  const float* __restrict__ Mpart,
                  const float* __restrict__ Lpart,
                  float* __restrict__ Yt) {
  const int idx = blockIdx.x * 256 + threadIdx.x;   // 0 .. B*N-1
  const int b = idx / NPOS, n = idx % NPOS;
  const float m0 = Mpart[(size_t)(b * KSPL + 0) * NPOS + n];
  const float m1 = Mpart[(size_t)(b * KSPL + 1) * NPOS + n];
  const float l0 = Lpart[(size_t)(b * KSPL + 0) * NPOS + n];
  const float l1 = Lpart[(size_t)(b * KSPL + 1) * NPOS + n];
  const float M  = fmaxf(m0, m1);
  const float w0 = __expf(m0 - M), w1 = __expf(m1 - M);
  const float inv = 1.0f / (w0 * l0 + w1 * l1);
  for (int d = 0; d < ICH; ++d) {
    const float o0 = Opart[((size_t)(b * KSPL + 0) * ICH + d) * NPOS + n];
    const float o1 = Opart[((size_t)(b * KSPL + 1) * ICH + d) * NPOS + n];
    Yt[((size_t)b * ICH + d) * NPOS + n] = (w0 * o0 + w1 * o1) * inv;
  }
}

// ---------------------------------------------------------------------------
// zres (R2-verbatim): out[b][c][n] = sum_ic Wz[c][ic] * Y^T[b][ic][n] + x
// ---------------------------------------------------------------------------
__global__ __launch_bounds__(256, 2)
void zres_kernel(const float* __restrict__ x,
                 const float* __restrict__ Wz,
                 const float* __restrict__ Yt,
                 float* __restrict__ out) {
  const int n0 = blockIdx.x * 64;
  const int c0 = blockIdx.y * 64;
  const int b  = blockIdx.z;
  __shared__ float Yts[64][17];              // [n][kk(ic)]
  __shared__ float Wzt[64][17];              // [c][kk]
  const int tid = threadIdx.x;
  const int tx = tid & 15, ty = tid >> 4;
  float acc[4][4] = {};                      // rows c = ty*4+i, cols n = tx*4+j

  for (int ic0 = 0; ic0 < ICH; ic0 += 16) {
    {
      const int nn = tid & 63, k4 = tid >> 6;
      #pragma unroll
      for (int q = 0; q < 4; ++q) {
        const int kk = k4 + q * 4;
        Yts[nn][kk] = Yt[((size_t)b * ICH + ic0 + kk) * NPOS + n0 + nn];
      }
      const int kk = tid & 15, rr = tid >> 4;
      #pragma unroll
      for (int q = 0; q < 4; ++q) {
        const int cc = rr + q * 16;
        Wzt[cc][kk] = Wz[(size_t)(c0 + cc) * ICH + ic0 + kk];
      }
    }
    __syncthreads();
    #pragma unroll
    for (int kk = 0; kk < 16; ++kk) {
      float a_[4], b_[4];
      #pragma unroll
      for (int i = 0; i < 4; ++i) a_[i] = Wzt[ty * 4 + i][kk];
      #pragma unroll
      for (int j = 0; j < 4; ++j) b_[j] = Yts[tx * 4 + j][kk];
      #pragma unroll
      for (int i = 0; i < 4; ++i)
        #pragma unroll
        for (int j = 0; j < 4; ++j) acc[i][j] += a_[i] * b_[j];
    }
    __syncthreads();
  }
  #pragma unroll
  for (int i = 0; i < 4; ++i) {
    const size_t base = ((size_t)(b * CCH + c0 + ty * 4 + i)) * NPOS + n0 + tx * 4;
    const float4 xr = *(const float4*)&x[base];
    float4 v;
    v.x = acc[i][0] + xr.x; v.y = acc[i][1] + xr.y;
    v.z = acc[i][2] + xr.z; v.w = acc[i][3] + xr.w;
    *(float4*)&out[base] = v;
  }
}

// ---------------------------------------------------------------------------
extern "C" void kernel_launch(void* const* d_in, const int* in_sizes, int n_in,
                              void* d_out, int out_size, void* d_ws, size_t ws_size,
                              hipStream_t stream) {
  const float* x      = (const float*)d_in[0];
  const float* Wg     = (const float*)d_in[1];
  const float* Wtheta = (const float*)d_in[2];
  const float* Wphi   = (const float*)d_in[3];
  const float* Wz     = (const float*)d_in[4];
  float* out = (float*)d_out;

  unsigned short* Qg  = (unsigned short*)d_ws;
  unsigned short* Kg  = Qg + BNIC;
  unsigned short* Vtg = Kg + BNIC;
  float* Opart = (float*)(Vtg + BNIC);             // KSPL * BNIC floats
  float* Mpart = Opart + (size_t)KSPL * BNIC;
  float* Lpart = Mpart + (size_t)BB * NPOS * KSPL / KSPL * KSPL; // = + KSPL*B*N
  // (explicit): Mpart length = KSPL*BB*NPOS floats
  Lpart = Mpart + (size_t)KSPL * BB * NPOS;
  float* Yt    = (float*)Qg;                       // overlay; written after flash2

  proj_qk<<<dim3(NPOS / 64, 4, BB), 256, 0, stream>>>(x, Wtheta, Wphi, Qg, Kg);
  proj_v <<<dim3(NPOS / 64, 2, BB), 256, 0, stream>>>(x, Wg, Vtg);
  flash2 <<<dim3(NPOS / 128, KSPL, BB), 256, 0, stream>>>(Qg, Kg, Vtg, Opart, Mpart, Lpart);
  merge_kernel<<<dim3(BB * NPOS / 256), 256, 0, stream>>>(Opart, Mpart, Lpart, Yt);
  zres_kernel<<<dim3(NPOS / 64, CCH / 64, BB), 256, 0, stream>>>(x, Wz, Yt, out);
}